// Round 5
// baseline (343.314 us; speedup 1.0000x reference)
//
#include <hip/hip_runtime.h>
#include <hip/hip_bf16.h>

#define BQ 4
#define QN 8192
#define DD 256
#define LL 2
#define H0c 128
#define W0c 128
#define H1c 64
#define W1c 64
#define EPSF 1e-5f

#define T0B 16384   // map0 transpose blocks
#define T1B 4096    // map1 transpose blocks

typedef unsigned short ushort_t;
typedef __attribute__((ext_vector_type(8))) short short8;
typedef __attribute__((ext_vector_type(8))) unsigned short ushortx8;
typedef __attribute__((ext_vector_type(4))) float floatx4;
typedef __attribute__((ext_vector_type(4))) _Float16 half4;

static __device__ __forceinline__ float lo16f(unsigned int d) {
    union { unsigned int u; float f; } x; x.u = d << 16; return x.f;
}
static __device__ __forceinline__ float hi16f(unsigned int d) {
    union { unsigned int u; float f; } x; x.u = d & 0xFFFF0000u; return x.f;
}
static __device__ __forceinline__ unsigned short f2bf(float f) {
    __hip_bfloat16 h = __float2bfloat16(f);
    return __builtin_bit_cast(unsigned short, h);
}

// ---------------- Kernel 1: prep_pack — WoutT transpose + weight pack + bbox init ----------------
// blocks [0,64): Wout transpose; [64,128): pack Wall/bias64 (+ bbox init in block 64)
__global__ __launch_bounds__(256) void prep_pack(const float* __restrict__ Wout,
                                                 const float* __restrict__ Wrd, const float* __restrict__ brd,
                                                 const float* __restrict__ Woff, const float* __restrict__ boff,
                                                 const float* __restrict__ Wattn, const float* __restrict__ battn,
                                                 __hip_bfloat16* __restrict__ WoutT,
                                                 float* __restrict__ Wall, float* __restrict__ bias64,
                                                 int* __restrict__ bb) {
    __shared__ float tile[32][33];
    int blk = blockIdx.x;
    int tx = threadIdx.x, ty = threadIdx.y;
    if (blk < 64) {
        int c0 = (blk / 8) * 32, hw0 = (blk % 8) * 32;
#pragma unroll
        for (int j = 0; j < 32; j += 8)
            tile[ty + j][tx] = Wout[(size_t)(c0 + ty + j) * DD + hw0 + tx];
        __syncthreads();
#pragma unroll
        for (int j = 0; j < 32; j += 8)
            WoutT[(size_t)(hw0 + ty + j) * DD + c0 + tx] = __float2bfloat16(tile[tx][ty + j]);
    } else {
        int l = blk - 64;
        int tid = ty * 32 + tx;
        int idx = l * 256 + tid;               // 0..16383
        int k = idx >> 6, c = idx & 63;
        float v = (c < 4)  ? Wrd[k * 4 + c]
                : (c < 36) ? Woff[k * 32 + (c - 4)]
                : (c < 52) ? Wattn[k * 16 + (c - 36)]
                : 0.f;
        Wall[idx] = v;
        if (idx < 64) {
            float bv = (idx < 4)  ? brd[idx]
                     : (idx < 36) ? boff[idx - 4]
                     : (idx < 52) ? battn[idx - 36]
                     : 0.f;
            bias64[idx] = bv;
        }
        if (idx < 16)      bb[idx] = 0x7fffffff;   // mins
        else if (idx < 32) bb[idx] = 0;            // maxs
    }
}

// ---------------- Kernel 2: proj GEMM (fp32) + descriptor epilogue + bbox atomics ----------------
__global__ __launch_bounds__(256) void proj_desc(const float* __restrict__ q,
                                                 const float* __restrict__ Wall,
                                                 const float* __restrict__ bias64,
                                                 const float* __restrict__ base_ref,
                                                 int2* __restrict__ dsi,
                                                 half4* __restrict__ dsw,
                                                 int* __restrict__ bb) {
    __shared__ float As[32][68];
    __shared__ float Bs[32][64];
    __shared__ float prs[64][68];
    __shared__ int lbb[8];   // [0..3]=min{x,y}l0,l1  [4..7]=max{x,y}l0,l1
    int tid = threadIdx.x;
    int tx = tid & 15, ty = tid >> 4;
    int m0 = blockIdx.x * 64;
    if (tid < 4) lbb[tid] = 0x7fffffff;
    else if (tid < 8) lbb[tid] = 0;
    float acc[4][4] = {};

    for (int kt = 0; kt < DD; kt += 32) {
#pragma unroll
        for (int j = 0; j < 8; j++) {
            int e = tid + 256 * j;
            int r = e >> 5, k = e & 31;
            As[k][r] = q[(size_t)(m0 + r) * DD + kt + k];
        }
#pragma unroll
        for (int j = 0; j < 8; j++) {
            int e = tid + 256 * j;
            int k = e >> 6, nn = e & 63;
            Bs[k][nn] = Wall[(size_t)(kt + k) * 64 + nn];
        }
        __syncthreads();
#pragma unroll
        for (int k = 0; k < 32; k++) {
            const float4 a4 = *(const float4*)&As[k][ty * 4];
            const float4 b4 = *(const float4*)&Bs[k][tx * 4];
            acc[0][0] += a4.x * b4.x; acc[0][1] += a4.x * b4.y; acc[0][2] += a4.x * b4.z; acc[0][3] += a4.x * b4.w;
            acc[1][0] += a4.y * b4.x; acc[1][1] += a4.y * b4.y; acc[1][2] += a4.y * b4.z; acc[1][3] += a4.y * b4.w;
            acc[2][0] += a4.z * b4.x; acc[2][1] += a4.z * b4.y; acc[2][2] += a4.z * b4.z; acc[2][3] += a4.z * b4.w;
            acc[3][0] += a4.w * b4.x; acc[3][1] += a4.w * b4.y; acc[3][2] += a4.w * b4.z; acc[3][3] += a4.w * b4.w;
        }
        __syncthreads();
    }

    float4 bias = *(const float4*)&bias64[tx * 4];
#pragma unroll
    for (int i = 0; i < 4; i++) {
        float4 v;
        v.x = acc[i][0] + bias.x;
        v.y = acc[i][1] + bias.y;
        v.z = acc[i][2] + bias.z;
        v.w = acc[i][3] + bias.w;
        *(float4*)&prs[ty * 4 + i][tx * 4] = v;
    }
    __syncthreads();

    int ql = tid >> 2, sq = tid & 3;
    int n = m0 + ql, b = n >> 13;        // QN = 8192; b uniform per block
    int lvl = sq >> 1;                   // this thread's 4 samples share a level
    const float* p = prs[ql];

    float mx = p[36];
#pragma unroll
    for (int i = 1; i < 16; i++) mx = fmaxf(mx, p[36 + i]);
    float sum = 0.f;
#pragma unroll
    for (int i = 0; i < 16; i++) sum += __expf(p[36 + i] - mx);
    float inv = 1.f / sum;

    int mnx = 0x7fffffff, mny = 0x7fffffff, mxx = 0, mxy = 0;

#pragma unroll
    for (int u = 0; u < 4; u++) {
        int s = sq * 4 + u;
        int l = s >> 3;
        float a = __expf(p[36 + s] - mx) * inv;

        int W = l ? W1c : W0c;
        int H = l ? H1c : H0c;
        float Wf = (float)W, Hf = (float)H;

        float bx = base_ref[(b * LL + l) * 2 + 0];
        float by = base_ref[(b * LL + l) * 2 + 1];
        bx = fminf(fmaxf(bx, EPSF), 1.f - EPSF);
        by = fminf(fmaxf(by, EPSF), 1.f - EPSF);
        float lgx = logf(bx / (1.f - bx));
        float lgy = logf(by / (1.f - by));
        float refx = 1.f / (1.f + __expf(-(lgx + p[l * 2 + 0])));
        float refy = 1.f / (1.f + __expf(-(lgy + p[l * 2 + 1])));

        float locx = refx + p[4 + s * 2 + 0] / Wf;
        float locy = refy + p[4 + s * 2 + 1] / Hf;
        if (l == 1) locy = locy - floorf(locy);   // jnp.remainder(y, 1.0)

        float gx = locx * 2.f - 1.f;
        float gy = locy * 2.f - 1.f;
        float x = ((gx + 1.f) * Wf - 1.f) * 0.5f;
        float y = ((gy + 1.f) * Hf - 1.f) * 0.5f;
        x = fminf(fmaxf(x, 0.f), Wf - 1.f);
        y = fminf(fmaxf(y, 0.f), Hf - 1.f);
        float x0f = floorf(x), y0f = floorf(y);
        float wx = x - x0f, wy = y - y0f;
        int x0 = (int)x0f, y0 = (int)y0f;
        unsigned int dx = (x0 + 1 <= W - 1) ? DD : 0;            // elems
        unsigned int dy = (y0 + 1 <= H - 1) ? (unsigned)(W * DD) : 0;
        int base = ((b * H + y0) * W + x0) * DD;

        mnx = min(mnx, x0); mny = min(mny, y0);
        mxx = max(mxx, x0 + (dx ? 1 : 0)); mxy = max(mxy, y0 + (dy ? 1 : 0));

        float omx = 1.f - wx, omy = 1.f - wy;
        half4 w;
        w[0] = (_Float16)(a * omx * omy);
        w[1] = (_Float16)(a * wx  * omy);
        w[2] = (_Float16)(a * omx * wy);
        w[3] = (_Float16)(a * wx  * wy);

        dsi[(size_t)n * 16 + s] = make_int2(base, (int)((dy << 16) | dx));
        dsw[(size_t)n * 16 + s] = w;
    }

    atomicMin(&lbb[lvl * 2 + 0], mnx);
    atomicMin(&lbb[lvl * 2 + 1], mny);
    atomicMax(&lbb[4 + lvl * 2 + 0], mxx);
    atomicMax(&lbb[4 + lvl * 2 + 1], mxy);
    __syncthreads();
    if (tid < 4)      atomicMin(&bb[(b * 2 + (tid >> 1)) * 2 + (tid & 1)], lbb[tid]);
    else if (tid < 8) atomicMax(&bb[16 + (b * 2 + ((tid - 4) >> 1)) * 2 + ((tid - 4) & 1)], lbb[tid]);
}

// ---------------- Kernel 3: bbox-gated map transpose (B,D,H,W) fp32 -> (B,H,W,D) bf16 ----------------
__global__ __launch_bounds__(256) void map_transpose(const float* __restrict__ map0, const float* __restrict__ map1,
                                                     __hip_bfloat16* __restrict__ mapT0, __hip_bfloat16* __restrict__ mapT1,
                                                     const int* __restrict__ bb) {
    __shared__ float tile[32][33];
    int blk = blockIdx.x;
    int tx = threadIdx.x, ty = threadIdx.y;
    const float* in; __hip_bfloat16* outp; int HW, b, c0, hw0, l, W;
    if (blk < T0B) {
        l = 0; b = blk / (512 * 8); int r = blk % (512 * 8);
        c0 = (r / 512) * 32; hw0 = (r % 512) * 32;
        in = map0; outp = mapT0; HW = H0c * W0c; W = W0c;
    } else {
        l = 1; int t = blk - T0B; b = t / (128 * 8); int r = t % (128 * 8);
        c0 = (r / 128) * 32; hw0 = (r % 128) * 32;
        in = map1; outp = mapT1; HW = H1c * W1c; W = W1c;
    }
    // gate: does this hw tile intersect the sampled bbox?
    int y = hw0 / W, xt = hw0 % W;       // tile = row y, cols [xt, xt+31]
    int bbi = (b * 2 + l) * 2;
    int mnx = bb[bbi], mny = bb[bbi + 1], mxx = bb[16 + bbi], mxy = bb[16 + bbi + 1];
    if (y < mny || y > mxy || xt > mxx || xt + 31 < mnx) return;

    const float* inb = in + (size_t)b * DD * HW;
    __hip_bfloat16* outb = outp + (size_t)b * DD * HW;
#pragma unroll
    for (int j = 0; j < 32; j += 8)
        tile[ty + j][tx] = inb[(size_t)(c0 + ty + j) * HW + hw0 + tx];
    __syncthreads();
#pragma unroll
    for (int j = 0; j < 32; j += 8)
        outb[(size_t)(hw0 + ty + j) * DD + c0 + tx] = __float2bfloat16(tile[tx][ty + j]);
}

// ---------------- Kernel 4: fused sampling + output MFMA ----------------
// Block = 16 queries. Phase 1: sample into LDS S tile (padded stride 264). Phase 2: MFMA vs WT, write out.
__global__ __launch_bounds__(256, 4) void sample_out(const ushort_t* __restrict__ mapT0,
                                                     const ushort_t* __restrict__ mapT1,
                                                     const int2* __restrict__ dsi,
                                                     const half4* __restrict__ dsw,
                                                     const ushort_t* __restrict__ WT,
                                                     const float* __restrict__ bout,
                                                     float* __restrict__ out) {
    __shared__ ushort_t S[16][264];   // 16 queries x 256 ch, +8 pad -> 2-way-free b128 reads
    int tid = threadIdx.x;
    int wave = tid >> 6, lane = tid & 63;
    int m0 = blockIdx.x * 16;
    int halfq = lane >> 5;
    int c8 = (lane & 31) * 8;

    // ---- phase 1: each wave samples 4 queries (2 per iter, 32 lanes x 8ch each) ----
#pragma unroll
    for (int iter = 0; iter < 2; iter++) {
        int nl = wave * 4 + iter * 2 + halfq;
        int n = m0 + nl;
        const int2*  gi = dsi + (size_t)n * 16;
        const half4* gw = dsw + (size_t)n * 16;
        int2 g[16]; half4 wh[16];
#pragma unroll
        for (int s = 0; s < 16; s++) { g[s] = gi[s]; wh[s] = gw[s]; }

        float acc[8];
#pragma unroll
        for (int i = 0; i < 8; i++) acc[i] = 0.f;

#pragma unroll
        for (int grp = 0; grp < 4; grp++) {
            const ushort_t* mp = (grp < 2) ? mapT0 : mapT1;
            uint4 u[4][4];
#pragma unroll
            for (int j = 0; j < 4; j++) {
                int s = grp * 4 + j;
                int dx = g[s].y & 0xffff;
                int dy = (int)(((unsigned int)g[s].y) >> 16);
                const ushort_t* p0 = mp + g[s].x + c8;
                u[j][0] = *(const uint4*)(p0);
                u[j][1] = *(const uint4*)(p0 + dx);
                u[j][2] = *(const uint4*)(p0 + dy);
                u[j][3] = *(const uint4*)(p0 + dx + dy);
            }
#pragma unroll
            for (int j = 0; j < 4; j++) {
                int s = grp * 4 + j;
                float w0 = (float)wh[s][0], w1 = (float)wh[s][1], w2 = (float)wh[s][2], w3 = (float)wh[s][3];
#pragma unroll
                for (int corner = 0; corner < 4; corner++) {
                    uint4 v = u[j][corner];
                    float wc = (corner == 0) ? w0 : (corner == 1) ? w1 : (corner == 2) ? w2 : w3;
                    acc[0] += wc * lo16f(v.x); acc[1] += wc * hi16f(v.x);
                    acc[2] += wc * lo16f(v.y); acc[3] += wc * hi16f(v.y);
                    acc[4] += wc * lo16f(v.z); acc[5] += wc * hi16f(v.z);
                    acc[6] += wc * lo16f(v.w); acc[7] += wc * hi16f(v.w);
                }
            }
        }
        ushortx8 o;
#pragma unroll
        for (int i = 0; i < 8; i++) o[i] = f2bf(acc[i]);
        *(ushortx8*)&S[nl][c8] = o;
    }
    __syncthreads();

    // ---- phase 2: MFMA 16x16x32, A from LDS S tile, B from WT (L2-hot), each wave 4 n-tiles ----
    int row = lane & 15, quad = lane >> 4;
    short8 a[8];
#pragma unroll
    for (int k = 0; k < 8; k++) a[k] = *(const short8*)&S[row][quad * 8 + k * 32];

#pragma unroll
    for (int j = 0; j < 4; j++) {
        int nt = wave * 4 + j;
        floatx4 acc4 = {0.f, 0.f, 0.f, 0.f};
#pragma unroll
        for (int k = 0; k < 8; k++) {
            short8 bfr = *(const short8*)(WT + (size_t)(nt * 16 + row) * DD + k * 32 + quad * 8);
            acc4 = __builtin_amdgcn_mfma_f32_16x16x32_bf16(a[k], bfr, acc4, 0, 0, 0);
        }
        float bv = bout[nt * 16 + row];
#pragma unroll
        for (int r = 0; r < 4; r++) {
            out[(size_t)(m0 + quad * 4 + r) * DD + nt * 16 + row] = acc4[r] + bv;
        }
    }
}

// ---------------- launch ----------------
extern "C" void kernel_launch(void* const* d_in, const int* in_sizes, int n_in,
                              void* d_out, int out_size, void* d_ws, size_t ws_size,
                              hipStream_t stream) {
    const float* q        = (const float*)d_in[0];
    const float* map0     = (const float*)d_in[1];
    const float* map1     = (const float*)d_in[2];
    const float* base_ref = (const float*)d_in[3];
    const float* Wrd      = (const float*)d_in[4];
    const float* brd      = (const float*)d_in[5];
    const float* Woff     = (const float*)d_in[6];
    const float* boff     = (const float*)d_in[7];
    const float* Wattn    = (const float*)d_in[8];
    const float* battn    = (const float*)d_in[9];
    const float* Wout     = (const float*)d_in[10];
    const float* bout     = (const float*)d_in[11];
    float* out = (float*)d_out;

    // workspace layout (bytes)
    char* ws = (char*)d_ws;
    __hip_bfloat16* mapT0  = (__hip_bfloat16*)(ws + 0);          // 33,554,432
    __hip_bfloat16* mapT1  = (__hip_bfloat16*)(ws + 33554432);   //  8,388,608
    __hip_bfloat16* WoutT  = (__hip_bfloat16*)(ws + 41943040);   //    131,072
    float*          Wall   = (float*)(ws + 42074112);            //     65,536
    float*          bias64 = (float*)(ws + 42139648);            //        256
    int2*           dsi    = (int2*)(ws + 42139904);             //  4,194,304
    half4*          dsw    = (half4*)(ws + 46334208);            //  4,194,304
    int*            bb     = (int*)(ws + 50528512);              //        128 (16 min + 16 max)

    // 1. Wout transpose + weight pack + bbox init
    prep_pack<<<dim3(128), dim3(32, 8), 0, stream>>>(
        Wout, Wrd, brd, Woff, boff, Wattn, battn, WoutT, Wall, bias64, bb);

    // 2. projections + descriptors + bbox
    proj_desc<<<dim3(BQ * QN / 64), dim3(256), 0, stream>>>(q, Wall, bias64, base_ref, dsi, dsw, bb);

    // 3. bbox-gated map transpose
    map_transpose<<<dim3(T0B + T1B), dim3(32, 8), 0, stream>>>(map0, map1, mapT0, mapT1, bb);

    // 4. fused sampling + output projection
    sample_out<<<dim3(BQ * QN / 16), dim3(256), 0, stream>>>(
        (const ushort_t*)mapT0, (const ushort_t*)mapT1, dsi, dsw,
        (const ushort_t*)WoutT, bout, out);
}